// Round 12
// baseline (1422.186 us; speedup 1.0000x reference)
//
#include <hip/hip_runtime.h>
#include <math.h>

// Problem constants
#define NROW 8192   // B*T
#define DIM  512
#define TT   2048
#define HH   4
#define DH   128
#define GG   2025   // GH*GW
#define GP   2032   // GG padded to %16
#define SS   2048
#define KTOP 40

// ---------------------------------------------------------------------------
// embed gather + layernorm:  x = table[tok], xn = LN(x)*g + b
// ---------------------------------------------------------------------------
__global__ __launch_bounds__(256) void k_embed_ln(
    const int* __restrict__ tokens, const float* __restrict__ table,
    const float* __restrict__ g, const float* __restrict__ b,
    float* __restrict__ x, float* __restrict__ xn)
{
    __shared__ float red[4];
    const int row = blockIdx.x;
    const int tid = threadIdx.x;
    const float* src = table + (size_t)tokens[row] * DIM;
    float v0 = src[tid], v1 = src[tid + 256];

    float s = v0 + v1;
    for (int off = 32; off; off >>= 1) s += __shfl_xor(s, off, 64);
    if ((tid & 63) == 0) red[tid >> 6] = s;
    __syncthreads();
    float mean = (red[0] + red[1] + red[2] + red[3]) * (1.0f / 512.0f);
    __syncthreads();

    float d0 = v0 - mean, d1 = v1 - mean;
    float ss = d0 * d0 + d1 * d1;
    for (int off = 32; off; off >>= 1) ss += __shfl_xor(ss, off, 64);
    if ((tid & 63) == 0) red[tid >> 6] = ss;
    __syncthreads();
    float var = (red[0] + red[1] + red[2] + red[3]) * (1.0f / 512.0f);
    float rs = 1.0f / sqrtf(var + 1e-5f);

    size_t base = (size_t)row * DIM;
    x[base + tid]        = v0;
    x[base + tid + 256]  = v1;
    xn[base + tid]       = d0 * rs * g[tid] + b[tid];
    xn[base + tid + 256] = d1 * rs * g[tid + 256] + b[tid + 256];
}

// ---------------------------------------------------------------------------
// f32 GEMM  C = epi(A @ B + bias). A: MxK, B: KxN row-major.
// 128x128 tile, BK=16, 256 thr, 8x8/thread. (proven rounds 4/6/7/11)
// KCH>0: split-K partials to C + z*M*N, no epilogue (proven round 10).
// EPI_QKVG: bias then sigmoid only for columns n>=1536 (gate block).
// EPI_GATERES: gate read with row stride gstride (packed-QKVG support).
// ---------------------------------------------------------------------------
enum { EPI_BIAS = 0, EPI_SIGMOID = 1, EPI_GATERES = 2, EPI_GELU = 3, EPI_NONE = 4, EPI_QKVG = 5 };

template<int EPI, int KCH = 0>
__global__ __launch_bounds__(256) void k_gemm_f32(
    const float* __restrict__ A, const float* __restrict__ B,
    const float* __restrict__ bias, float* __restrict__ C,
    int M, int N, int K,
    const float* __restrict__ resid, const float* __restrict__ gate, int gstride)
{
    __shared__ float As[16][132];   // [k][m]
    __shared__ float Bs[16][132];   // [k][n]
    const int tid = threadIdx.x;
    const int tx = tid & 15, ty = tid >> 4;
    const int bm = blockIdx.y * 128, bn = blockIdx.x * 128;
    float acc[8][8] = {};

    int kbeg = 0, kend = K;
    float* Cw = C;
    if (KCH > 0) {
        kbeg = blockIdx.z * KCH;
        kend = min(kbeg + KCH, K);
        Cw = C + (size_t)blockIdx.z * M * N;
    }

    const int a_m = tid >> 2;
    const int a_c = (tid & 3) * 4;
    const int b_r = tid >> 5;
    const int b_n = (tid & 31) * 4;

    const float* Arow0 = A + (size_t)(bm + a_m) * K + a_c;
    const float* Arow1 = A + (size_t)(bm + a_m + 64) * K + a_c;
    const float* Brow0 = B + (size_t)b_r * N + bn + b_n;
    const float* Brow1 = B + (size_t)(b_r + 8) * N + bn + b_n;

    for (int k0 = kbeg; k0 < kend; k0 += 16) {
        float4 av0 = *(const float4*)(Arow0 + k0);
        float4 av1 = *(const float4*)(Arow1 + k0);
        float4 bv0 = *(const float4*)(Brow0 + (size_t)k0 * N);
        float4 bv1 = *(const float4*)(Brow1 + (size_t)k0 * N);
        __syncthreads();
        As[a_c + 0][a_m] = av0.x; As[a_c + 1][a_m] = av0.y;
        As[a_c + 2][a_m] = av0.z; As[a_c + 3][a_m] = av0.w;
        As[a_c + 0][a_m + 64] = av1.x; As[a_c + 1][a_m + 64] = av1.y;
        As[a_c + 2][a_m + 64] = av1.z; As[a_c + 3][a_m + 64] = av1.w;
        *(float4*)&Bs[b_r][b_n]     = bv0;
        *(float4*)&Bs[b_r + 8][b_n] = bv1;
        __syncthreads();
#pragma unroll
        for (int kk = 0; kk < 16; ++kk) {
            float4 a0 = *(const float4*)&As[kk][ty * 4];
            float4 a1 = *(const float4*)&As[kk][64 + ty * 4];
            float4 b0 = *(const float4*)&Bs[kk][tx * 4];
            float4 b1 = *(const float4*)&Bs[kk][64 + tx * 4];
            float av[8] = {a0.x, a0.y, a0.z, a0.w, a1.x, a1.y, a1.z, a1.w};
            float bv[8] = {b0.x, b0.y, b0.z, b0.w, b1.x, b1.y, b1.z, b1.w};
#pragma unroll
            for (int i = 0; i < 8; ++i)
#pragma unroll
                for (int j = 0; j < 8; ++j)
                    acc[i][j] = fmaf(av[i], bv[j], acc[i][j]);
        }
    }

#pragma unroll
    for (int i = 0; i < 8; ++i) {
        int m = bm + 4 * ty + (i & 3) + (i >> 2) * 64;
#pragma unroll
        for (int half = 0; half < 2; ++half) {
            int n0 = bn + 4 * tx + half * 64;
            size_t idx = (size_t)m * N + n0;
            float4 o;
            float* oo = (float*)&o;
#pragma unroll
            for (int j = 0; j < 4; ++j) {
                float t = acc[i][half * 4 + j];
                if (EPI != EPI_NONE && KCH == 0) t += bias[n0 + j];
                float r;
                if (KCH > 0)                 r = t;
                else if (EPI == EPI_SIGMOID) r = 1.0f / (1.0f + expf(-t));
                else if (EPI == EPI_QKVG)    r = (n0 + j >= 1536) ? 1.0f / (1.0f + expf(-t)) : t;
                else if (EPI == EPI_GATERES) r = resid[idx + j] + gate[(size_t)m * gstride + n0 + j] * t;
                else if (EPI == EPI_GELU)    r = 0.5f * t * (1.0f + erff(t * 0.70710678118654752440f));
                else                         r = t;
                oo[j] = r;
            }
            *(float4*)&Cw[idx] = o;
        }
    }
}

// ---------------------------------------------------------------------------
// f32 GEMM, 256x128 tile, BK=16, 256 thr, 16x8/thread. NO min-waves cap:
// ~200 VGPR, 2 waves/SIMD, zero spill (round-10's cap at 128 VGPR caused the
// spill regression). 0.75 B LDS per FMA -> VALU-bound. Per-output k-order
// identical to k_gemm_f32 -> bitwise-same. M%256==0, N%128==0, K%16==0.
// ---------------------------------------------------------------------------
template<int EPI>
__global__ __launch_bounds__(256) void k_gemm_f32_big(
    const float* __restrict__ A, const float* __restrict__ B,
    const float* __restrict__ bias, float* __restrict__ C,
    int M, int N, int K)
{
    __shared__ float As[16][260];   // [k][m]  (256 + pad 4)
    __shared__ float Bs[16][132];   // [k][n]
    const int tid = threadIdx.x;
    const int tx = tid & 15, ty = tid >> 4;
    const int bm = blockIdx.y * 256, bn = blockIdx.x * 128;
    float acc[16][8] = {};

    const int a_m = tid >> 2;          // 0..63 (also +64,+128,+192)
    const int a_c = (tid & 3) * 4;     // k-offset {0,4,8,12}
    const int b_r = tid >> 5;          // 0..7  (also +8)
    const int b_n = (tid & 31) * 4;

    const float* Br0 = B + (size_t)b_r * N + bn + b_n;
    const float* Br1 = B + (size_t)(b_r + 8) * N + bn + b_n;

    for (int k0 = 0; k0 < K; k0 += 16) {
        float4 av[4];
#pragma unroll
        for (int q = 0; q < 4; ++q)
            av[q] = *(const float4*)(A + (size_t)(bm + a_m + 64 * q) * K + k0 + a_c);
        float4 bv0 = *(const float4*)(Br0 + (size_t)k0 * N);
        float4 bv1 = *(const float4*)(Br1 + (size_t)k0 * N);
        __syncthreads();
#pragma unroll
        for (int q = 0; q < 4; ++q) {
            As[a_c + 0][a_m + 64 * q] = av[q].x;
            As[a_c + 1][a_m + 64 * q] = av[q].y;
            As[a_c + 2][a_m + 64 * q] = av[q].z;
            As[a_c + 3][a_m + 64 * q] = av[q].w;
        }
        *(float4*)&Bs[b_r][b_n]     = bv0;
        *(float4*)&Bs[b_r + 8][b_n] = bv1;
        __syncthreads();
#pragma unroll
        for (int kk = 0; kk < 16; ++kk) {
            float am[16], bn_[8];
#pragma unroll
            for (int q = 0; q < 4; ++q) {
                float4 t = *(const float4*)&As[kk][ty * 4 + 64 * q];
                am[q * 4 + 0] = t.x; am[q * 4 + 1] = t.y;
                am[q * 4 + 2] = t.z; am[q * 4 + 3] = t.w;
            }
            float4 u0 = *(const float4*)&Bs[kk][tx * 4];
            float4 u1 = *(const float4*)&Bs[kk][64 + tx * 4];
            bn_[0] = u0.x; bn_[1] = u0.y; bn_[2] = u0.z; bn_[3] = u0.w;
            bn_[4] = u1.x; bn_[5] = u1.y; bn_[6] = u1.z; bn_[7] = u1.w;
#pragma unroll
            for (int i = 0; i < 16; ++i)
#pragma unroll
                for (int j = 0; j < 8; ++j)
                    acc[i][j] = fmaf(am[i], bn_[j], acc[i][j]);
        }
    }

#pragma unroll
    for (int i = 0; i < 16; ++i) {
        int m = bm + 4 * ty + (i & 3) + (i >> 2) * 64;
#pragma unroll
        for (int half = 0; half < 2; ++half) {
            int n0 = bn + 4 * tx + half * 64;
            size_t idx = (size_t)m * N + n0;
            float4 o;
            float* oo = (float*)&o;
#pragma unroll
            for (int j = 0; j < 4; ++j) {
                float t = acc[i][half * 4 + j];
                if (EPI != EPI_NONE) t += bias[n0 + j];
                float r;
                if (EPI == EPI_QKVG)      r = (n0 + j >= 1536) ? 1.0f / (1.0f + expf(-t)) : t;
                else if (EPI == EPI_GELU) r = 0.5f * t * (1.0f + erff(t * 0.70710678118654752440f));
                else                      r = t;
                oo[j] = r;
            }
            *(float4*)&C[idx] = o;
        }
    }
}

// Wf[i] = p0+p1+p2+p3 (float4-wide), in place over p0  (proven round 10)
__global__ __launch_bounds__(256) void k_add4(float4* __restrict__ p, int n4)
{
    const int i = blockIdx.x * 256 + threadIdx.x;
    if (i >= n4) return;
    float4 a = p[i], b = p[i + n4], c = p[i + 2 * n4], d = p[i + 3 * n4];
    a.x += b.x + c.x + d.x; a.y += b.y + c.y + d.y;
    a.z += b.z + c.z + d.z; a.w += b.w + c.w + d.w;
    p[i] = a;
}

// ---------------------------------------------------------------------------
// pack wq|wk|wv|wg -> wpack (512x2048) and biases -> bpack (2048)
// ---------------------------------------------------------------------------
__global__ __launch_bounds__(256) void k_pack_qkvg(
    const float* __restrict__ wq, const float* __restrict__ wk,
    const float* __restrict__ wv, const float* __restrict__ wg,
    const float* __restrict__ bq, const float* __restrict__ bk,
    const float* __restrict__ bv, const float* __restrict__ bg,
    float* __restrict__ wpack, float* __restrict__ bpack)
{
    const int idx = blockIdx.x * 256 + threadIdx.x;   // 512*2048
    const int k = idx >> 11, n = idx & 2047;
    const int sel = n >> 9, nn = n & 511;
    const float* w = (sel == 0) ? wq : (sel == 1) ? wk : (sel == 2) ? wv : wg;
    wpack[idx] = w[(size_t)k * 512 + nn];
    if (idx < 2048) {
        const float* bb = (sel == 0) ? bq : (sel == 1) ? bk : (sel == 2) ? bv : bg;
        bpack[idx] = bb[nn];
    }
}

// ---------------------------------------------------------------------------
// banded attention over packed QKVG (row stride 2048; q@0,k@512,v@1024).
// window half-width 5 (W=11). One wave per (b,t,h). out: 8192x512.
// ---------------------------------------------------------------------------
__global__ __launch_bounds__(256) void k_attn(
    const float* __restrict__ qkvg, float* __restrict__ out)
{
    const int w    = (blockIdx.x << 2) + (threadIdx.x >> 6);
    const int lane = threadIdx.x & 63;
    const int h = w & 3;
    const int t = (w >> 2) & 2047;
    const int b = w >> 13;
    const size_t qb = ((size_t)(b * TT + t)) * 2048 + h * DH;
    const float q0 = qkvg[qb + lane], q1 = qkvg[qb + 64 + lane];

    float s[11];
#pragma unroll
    for (int o = 0; o < 11; ++o) {
        int pos = t + o - 5;
        bool valid = (pos >= 0 && pos < TT);
        float p = 0.0f;
        if (valid) {
            size_t kb = ((size_t)(b * TT + pos)) * 2048 + 512 + h * DH;
            p = q0 * qkvg[kb + lane] + q1 * qkvg[kb + 64 + lane];
        }
        for (int off = 32; off; off >>= 1) p += __shfl_xor(p, off, 64);
        s[o] = valid ? p / sqrtf(128.0f) : -1e9f;
    }
    float m = s[0];
#pragma unroll
    for (int o = 1; o < 11; ++o) m = fmaxf(m, s[o]);
    float e[11], sum = 0.0f;
#pragma unroll
    for (int o = 0; o < 11; ++o) { e[o] = expf(s[o] - m); sum += e[o]; }

    float o0 = 0.0f, o1 = 0.0f;
#pragma unroll
    for (int o = 0; o < 11; ++o) {
        int pos = t + o - 5;
        if (pos < 0 || pos >= TT) continue;
        float a = e[o] / sum;
        size_t vb = ((size_t)(b * TT + pos)) * 2048 + 1024 + h * DH;
        o0 = fmaf(a, qkvg[vb + lane], o0);
        o1 = fmaf(a, qkvg[vb + 64 + lane], o1);
    }
    const size_t ob = ((size_t)(b * TT + t)) * DIM + h * DH;
    out[ob + lane]      = o0;
    out[ob + 64 + lane] = o1;
}

// ---------------------------------------------------------------------------
// wf2f[q,s] = sum_p L[q,p] * wf[p,s]  (f64 accumulate, f32 out; GP rows)
// ---------------------------------------------------------------------------
__global__ __launch_bounds__(256) void k_conv_wf(
    const float* __restrict__ wf, float* __restrict__ wf2f)
{
    __shared__ float w[25];
    const int qq = blockIdx.x;
    if (qq >= GG) {
        for (int s = threadIdx.x; s < SS; s += 256)
            wf2f[(size_t)qq * SS + s] = 0.0f;
        return;
    }
    const int y = qq / 45, x = qq % 45;
    if (threadIdx.x < 25) {
        int ki = threadIdx.x / 5, kj = threadIdx.x % 5;
        double gi = exp(-0.5 * (double)((ki - 2) * (ki - 2)));
        double gj = exp(-0.5 * (double)((kj - 2) * (kj - 2)));
        double Z  = 1.0 + 2.0 * exp(-0.5) + 2.0 * exp(-2.0);
        w[threadIdx.x] = (float)(gi * gj / (Z * Z));
    }
    __syncthreads();
    for (int s = threadIdx.x; s < SS; s += 256) {
        double acc = 0.0;
#pragma unroll
        for (int dy = -2; dy <= 2; ++dy) {
            int yy = y + dy;
            if (yy < 0 || yy >= 45) continue;
#pragma unroll
            for (int dx = -2; dx <= 2; ++dx) {
                int xx2 = x + dx;
                if (xx2 < 0 || xx2 >= 45) continue;
                acc = fma((double)w[(dy + 2) * 5 + (dx + 2)],
                          (double)wf[(size_t)(yy * 45 + xx2) * SS + s], acc);
            }
        }
        wf2f[(size_t)qq * SS + s] = (float)acc;
    }
}

// w2pad[m][p] = p < GG ? w2[m][p] : 0   (1024 x GP)
__global__ __launch_bounds__(256) void k_pad_w2(
    const float* __restrict__ w2, float* __restrict__ w2pad)
{
    const size_t idx = (size_t)blockIdx.x * 256 + threadIdx.x;
    if (idx >= (size_t)1024 * GP) return;
    const int m = (int)(idx / GP), p = (int)(idx % GP);
    w2pad[idx] = (p < GG) ? w2[(size_t)m * GG + p] : 0.0f;
}

// c[s] = sum_q b2[q] * wf2f[q,s]  (f64 accumulate, f32 out)
__global__ __launch_bounds__(256) void k_bias_c(
    const float* __restrict__ b2, const float* __restrict__ wf2f,
    float* __restrict__ c)
{
    const int s = blockIdx.x * 4 + (threadIdx.x >> 6);
    const int lane = threadIdx.x & 63;
    double acc = 0.0;
    for (int qq = lane; qq < GG; qq += 64)
        acc = fma((double)b2[qq], (double)wf2f[(size_t)qq * SS + s], acc);
    for (int off = 32; off; off >>= 1) acc += __shfl_xor(acc, off, 64);
    if (lane == 0) c[s] = (float)acc;
}

// ---------------------------------------------------------------------------
// top-40 one-hot per row of 2048; iterative argmax, tie -> lower index
// ---------------------------------------------------------------------------
__global__ __launch_bounds__(256) void k_topk(
    const float* __restrict__ scores, float* __restrict__ sdr)
{
    __shared__ float vals[SS];
    __shared__ float rv[4];
    __shared__ int   ri[4];
    const int row = blockIdx.x;
    const float* srow = scores + (size_t)row * SS;
    float* drow = sdr + (size_t)row * SS;
    for (int i = threadIdx.x; i < SS; i += 256) { vals[i] = srow[i]; drow[i] = 0.0f; }
    __syncthreads();
    const int lane = threadIdx.x & 63, wid = threadIdx.x >> 6;
    for (int it = 0; it < KTOP; ++it) {
        float bv = -INFINITY; int bi = 0x7fffffff;
        for (int i = threadIdx.x; i < SS; i += 256) {
            float vv = vals[i];
            if (vv > bv) { bv = vv; bi = i; }
        }
        for (int off = 32; off; off >>= 1) {
            float ov = __shfl_xor(bv, off, 64);
            int   oi = __shfl_xor(bi, off, 64);
            if (ov > bv || (ov == bv && oi < bi)) { bv = ov; bi = oi; }
        }
        if (lane == 0) { rv[wid] = bv; ri[wid] = bi; }
        __syncthreads();
        if (threadIdx.x == 0) {
            float fv = rv[0]; int fi = ri[0];
            for (int wdx = 1; wdx < 4; ++wdx)
                if (rv[wdx] > fv || (rv[wdx] == fv && ri[wdx] < fi)) { fv = rv[wdx]; fi = ri[wdx]; }
            vals[fi] = -INFINITY;
            drow[fi] = 1.0f;
        }
        __syncthreads();
    }
}

// ---------------------------------------------------------------------------
// Buffer plan (identical to round 11, which passed):
//  1 embed_ln -> x@s0+0, xn@s0+3SZ
//  2 pack_qkvg -> wpack@s0+SZ, bpack@s0+SZ+1M
//  3 QKVG GEMM (big) -> qkvg@s1
//  4 attn -> attn@s0+SZ; 5 gateres -> ctx@s0+2SZ; 6 gelu -> h1@s0[0..2SZ)
//  7 conv_wf -> wf2f@s1; 8 pad_w2 -> w2pad@s1+SZ
//  9 W splitK x4 -> Wp@s0[2SZ..4SZ); 10 add4 -> Wf@s0+2SZ
// 11 bias_c -> cvec@s0+3SZ
// 12 scores GEMM (big) -> scores@s1
// 13 topk -> sdr@s0
// ---------------------------------------------------------------------------
extern "C" void kernel_launch(void* const* d_in, const int* in_sizes, int n_in,
                              void* d_out, int out_size, void* d_ws, size_t ws_size,
                              hipStream_t stream)
{
    (void)d_ws; (void)ws_size; (void)in_sizes; (void)n_in; (void)out_size;

    const int*   tokens = (const int*)d_in[0];
    const float* table  = (const float*)d_in[1];
    const float* ln_g   = (const float*)d_in[2];
    const float* ln_b   = (const float*)d_in[3];
    const float* wq = (const float*)d_in[4];  const float* bq = (const float*)d_in[5];
    const float* wk = (const float*)d_in[6];  const float* bk = (const float*)d_in[7];
    const float* wv = (const float*)d_in[8];  const float* bv = (const float*)d_in[9];
    const float* wo = (const float*)d_in[10]; const float* bo = (const float*)d_in[11];
    const float* wg = (const float*)d_in[12]; const float* bg = (const float*)d_in[13];
    const float* w1 = (const float*)d_in[14]; const float* b1 = (const float*)d_in[15];
    const float* w2 = (const float*)d_in[16]; const float* b2 = (const float*)d_in[17];
    const float* wf = (const float*)d_in[18];

    const size_t SZ = (size_t)NROW * DIM;          // 4,194,304 floats
    const size_t MEG = 1u << 20;
    float* slot0 = (float*)d_out;
    float* slot1 = slot0 + (size_t)NROW * SS;

    float* x     = slot0;
    float* wpack = slot0 + SZ;                 // 512x2048
    float* bpack = slot0 + SZ + MEG;           // 2048
    float* attn  = slot0 + SZ;                 // after QKVG GEMM (wpack dead)
    float* ctx   = slot0 + 2 * SZ;
    float* xn    = slot0 + 3 * SZ;
    float* qkvg  = slot1;                      // 8192x2048
    float* h1    = slot0;                      // 8192x1024
    float* wf2f  = slot1;                      // GPx2048
    float* w2pad = slot1 + SZ;                 // 1024xGP
    float* Wp    = slot0 + 2 * SZ;             // 4 partials 1024x2048 (= 2SZ)
    float* Wf    = Wp;                         // reduced in place
    float* cvec  = slot0 + 3 * SZ;             // 2048
    float* scores = slot1;
    float* sdr    = slot0;

    dim3 blk(256);
    dim3 gQKVG(16, 32);                       // big: 256x128, N=2048
    dim3 g512(4, 64);                         // N=512
    dim3 gGelu(8, 64);                        // N=1024 (128x128)
    dim3 gWs(16, 8, 4);                       // W split-K x4
    dim3 gSC(16, 32);                         // big: 256x128, N=2048

    k_embed_ln<<<NROW, blk, 0, stream>>>(tokens, table, ln_g, ln_b, x, xn);
    k_pack_qkvg<<<4096, blk, 0, stream>>>(wq, wk, wv, wg, bq, bk, bv, bg, wpack, bpack);
    k_gemm_f32_big<EPI_QKVG> <<<gQKVG, blk, 0, stream>>>(xn, wpack, bpack, qkvg, NROW, 2048, DIM);
    k_attn                   <<<NROW,  blk, 0, stream>>>(qkvg, attn);
    k_gemm_f32<EPI_GATERES>  <<<g512,  blk, 0, stream>>>(attn, wo, bo, ctx, NROW, DIM, DIM, x, qkvg + 1536, 2048);
    k_gemm_f32<EPI_GELU>     <<<gGelu, blk, 0, stream>>>(ctx, w1, b1, h1, NROW, 2 * DIM, DIM, nullptr, nullptr, 0);
    k_conv_wf                <<<GP,    blk, 0, stream>>>(wf, wf2f);
    k_pad_w2                 <<<(1024 * GP + 255) / 256, blk, 0, stream>>>(w2, w2pad);
    k_gemm_f32<EPI_NONE, 512><<<gWs,   blk, 0, stream>>>(w2pad, wf2f, nullptr, Wp, 1024, SS, GP, nullptr, nullptr, 0);
    k_add4                   <<<2048,  blk, 0, stream>>>((float4*)Wp, 524288);
    k_bias_c                 <<<SS/4,  blk, 0, stream>>>(b2, wf2f, cvec);
    k_gemm_f32_big<EPI_BIAS> <<<gSC,   blk, 0, stream>>>(h1, Wf, cvec, scores, NROW, SS, 2 * DIM);
    k_topk                   <<<NROW,  blk, 0, stream>>>(scores, sdr);
}

// Round 13
// 1286.905 us; speedup vs baseline: 1.1051x; 1.1051x over previous
//
#include <hip/hip_runtime.h>
#include <math.h>

// Problem constants
#define NROW 8192   // B*T
#define DIM  512
#define TT   2048
#define HH   4
#define DH   128
#define GG   2025   // GH*GW
#define GP   2032   // GG padded to %16
#define SS   2048
#define KTOP 40

// ---------------------------------------------------------------------------
// embed gather + layernorm:  x = table[tok], xn = LN(x)*g + b
// ---------------------------------------------------------------------------
__global__ __launch_bounds__(256) void k_embed_ln(
    const int* __restrict__ tokens, const float* __restrict__ table,
    const float* __restrict__ g, const float* __restrict__ b,
    float* __restrict__ x, float* __restrict__ xn)
{
    __shared__ float red[4];
    const int row = blockIdx.x;
    const int tid = threadIdx.x;
    const float* src = table + (size_t)tokens[row] * DIM;
    float v0 = src[tid], v1 = src[tid + 256];

    float s = v0 + v1;
    for (int off = 32; off; off >>= 1) s += __shfl_xor(s, off, 64);
    if ((tid & 63) == 0) red[tid >> 6] = s;
    __syncthreads();
    float mean = (red[0] + red[1] + red[2] + red[3]) * (1.0f / 512.0f);
    __syncthreads();

    float d0 = v0 - mean, d1 = v1 - mean;
    float ss = d0 * d0 + d1 * d1;
    for (int off = 32; off; off >>= 1) ss += __shfl_xor(ss, off, 64);
    if ((tid & 63) == 0) red[tid >> 6] = ss;
    __syncthreads();
    float var = (red[0] + red[1] + red[2] + red[3]) * (1.0f / 512.0f);
    float rs = 1.0f / sqrtf(var + 1e-5f);

    size_t base = (size_t)row * DIM;
    x[base + tid]        = v0;
    x[base + tid + 256]  = v1;
    xn[base + tid]       = d0 * rs * g[tid] + b[tid];
    xn[base + tid + 256] = d1 * rs * g[tid + 256] + b[tid + 256];
}

// ---------------------------------------------------------------------------
// f32 GEMM  C = epi(A @ B + bias). A: MxK, B: KxN row-major.
// 128x128 tile, BK=16, 256 thr, 8x8/thread. (structure proven rounds 4..11)
// Round 13: register prefetch — loads for tile k+1 are issued between the
// LDS write and the FMA block of tile k, hiding global-load latency under
// 1024 FMA-cycles. Per-output k accumulation order unchanged -> bitwise-
// identical results to rounds 7/11.
// KCH>0: split-K partials to C + z*M*N, no epilogue (proven round 10).
// EPI_QKVG: bias then sigmoid only for columns n>=1536 (gate block).
// EPI_GATERES: gate read with row stride gstride (packed-QKVG support).
// ---------------------------------------------------------------------------
enum { EPI_BIAS = 0, EPI_SIGMOID = 1, EPI_GATERES = 2, EPI_GELU = 3, EPI_NONE = 4, EPI_QKVG = 5 };

template<int EPI, int KCH = 0>
__global__ __launch_bounds__(256) void k_gemm_f32(
    const float* __restrict__ A, const float* __restrict__ B,
    const float* __restrict__ bias, float* __restrict__ C,
    int M, int N, int K,
    const float* __restrict__ resid, const float* __restrict__ gate, int gstride)
{
    __shared__ float As[16][132];   // [k][m]
    __shared__ float Bs[16][132];   // [k][n]
    const int tid = threadIdx.x;
    const int tx = tid & 15, ty = tid >> 4;
    const int bm = blockIdx.y * 128, bn = blockIdx.x * 128;
    float acc[8][8] = {};

    int kbeg = 0, kend = K;
    float* Cw = C;
    if (KCH > 0) {
        kbeg = blockIdx.z * KCH;
        kend = min(kbeg + KCH, K);
        Cw = C + (size_t)blockIdx.z * M * N;
    }

    const int a_m = tid >> 2;
    const int a_c = (tid & 3) * 4;
    const int b_r = tid >> 5;
    const int b_n = (tid & 31) * 4;

    const float* Arow0 = A + (size_t)(bm + a_m) * K + a_c;
    const float* Arow1 = A + (size_t)(bm + a_m + 64) * K + a_c;
    const float* Brow0 = B + (size_t)b_r * N + bn + b_n;
    const float* Brow1 = B + (size_t)(b_r + 8) * N + bn + b_n;

    // prologue: load first tile
    float4 av0 = *(const float4*)(Arow0 + kbeg);
    float4 av1 = *(const float4*)(Arow1 + kbeg);
    float4 bv0 = *(const float4*)(Brow0 + (size_t)kbeg * N);
    float4 bv1 = *(const float4*)(Brow1 + (size_t)kbeg * N);

    for (int k0 = kbeg; k0 < kend; k0 += 16) {
        __syncthreads();                       // prev-tile LDS reads done
        As[a_c + 0][a_m] = av0.x; As[a_c + 1][a_m] = av0.y;
        As[a_c + 2][a_m] = av0.z; As[a_c + 3][a_m] = av0.w;
        As[a_c + 0][a_m + 64] = av1.x; As[a_c + 1][a_m + 64] = av1.y;
        As[a_c + 2][a_m + 64] = av1.z; As[a_c + 3][a_m + 64] = av1.w;
        *(float4*)&Bs[b_r][b_n]     = bv0;
        *(float4*)&Bs[b_r + 8][b_n] = bv1;
        __syncthreads();                       // tile ready
        // prefetch next tile into registers; vmcnt-wait lands at next LDS
        // write, hidden under this tile's 1024 FMA cycles
        if (k0 + 16 < kend) {
            av0 = *(const float4*)(Arow0 + k0 + 16);
            av1 = *(const float4*)(Arow1 + k0 + 16);
            bv0 = *(const float4*)(Brow0 + (size_t)(k0 + 16) * N);
            bv1 = *(const float4*)(Brow1 + (size_t)(k0 + 16) * N);
        }
#pragma unroll
        for (int kk = 0; kk < 16; ++kk) {
            float4 a0 = *(const float4*)&As[kk][ty * 4];
            float4 a1 = *(const float4*)&As[kk][64 + ty * 4];
            float4 b0 = *(const float4*)&Bs[kk][tx * 4];
            float4 b1 = *(const float4*)&Bs[kk][64 + tx * 4];
            float av[8] = {a0.x, a0.y, a0.z, a0.w, a1.x, a1.y, a1.z, a1.w};
            float bv[8] = {b0.x, b0.y, b0.z, b0.w, b1.x, b1.y, b1.z, b1.w};
#pragma unroll
            for (int i = 0; i < 8; ++i)
#pragma unroll
                for (int j = 0; j < 8; ++j)
                    acc[i][j] = fmaf(av[i], bv[j], acc[i][j]);
        }
    }

#pragma unroll
    for (int i = 0; i < 8; ++i) {
        int m = bm + 4 * ty + (i & 3) + (i >> 2) * 64;
#pragma unroll
        for (int half = 0; half < 2; ++half) {
            int n0 = bn + 4 * tx + half * 64;
            size_t idx = (size_t)m * N + n0;
            float4 o;
            float* oo = (float*)&o;
#pragma unroll
            for (int j = 0; j < 4; ++j) {
                float t = acc[i][half * 4 + j];
                if (EPI != EPI_NONE && KCH == 0) t += bias[n0 + j];
                float r;
                if (KCH > 0)                 r = t;
                else if (EPI == EPI_SIGMOID) r = 1.0f / (1.0f + expf(-t));
                else if (EPI == EPI_QKVG)    r = (n0 + j >= 1536) ? 1.0f / (1.0f + expf(-t)) : t;
                else if (EPI == EPI_GATERES) r = resid[idx + j] + gate[(size_t)m * gstride + n0 + j] * t;
                else if (EPI == EPI_GELU)    r = 0.5f * t * (1.0f + erff(t * 0.70710678118654752440f));
                else                         r = t;
                oo[j] = r;
            }
            *(float4*)&Cw[idx] = o;
        }
    }
}

// Wf[i] = p0+p1+p2+p3 (float4-wide), in place over p0  (proven round 10)
__global__ __launch_bounds__(256) void k_add4(float4* __restrict__ p, int n4)
{
    const int i = blockIdx.x * 256 + threadIdx.x;
    if (i >= n4) return;
    float4 a = p[i], b = p[i + n4], c = p[i + 2 * n4], d = p[i + 3 * n4];
    a.x += b.x + c.x + d.x; a.y += b.y + c.y + d.y;
    a.z += b.z + c.z + d.z; a.w += b.w + c.w + d.w;
    p[i] = a;
}

// ---------------------------------------------------------------------------
// pack wq|wk|wv|wg -> wpack (512x2048) and biases -> bpack (2048)
// ---------------------------------------------------------------------------
__global__ __launch_bounds__(256) void k_pack_qkvg(
    const float* __restrict__ wq, const float* __restrict__ wk,
    const float* __restrict__ wv, const float* __restrict__ wg,
    const float* __restrict__ bq, const float* __restrict__ bk,
    const float* __restrict__ bv, const float* __restrict__ bg,
    float* __restrict__ wpack, float* __restrict__ bpack)
{
    const int idx = blockIdx.x * 256 + threadIdx.x;   // 512*2048
    const int k = idx >> 11, n = idx & 2047;
    const int sel = n >> 9, nn = n & 511;
    const float* w = (sel == 0) ? wq : (sel == 1) ? wk : (sel == 2) ? wv : wg;
    wpack[idx] = w[(size_t)k * 512 + nn];
    if (idx < 2048) {
        const float* bb = (sel == 0) ? bq : (sel == 1) ? bk : (sel == 2) ? bv : bg;
        bpack[idx] = bb[nn];
    }
}

// ---------------------------------------------------------------------------
// banded attention over packed QKVG (row stride 2048; q@0,k@512,v@1024).
// window half-width 5 (W=11). One wave per (b,t,h). out: 8192x512.
// ---------------------------------------------------------------------------
__global__ __launch_bounds__(256) void k_attn(
    const float* __restrict__ qkvg, float* __restrict__ out)
{
    const int w    = (blockIdx.x << 2) + (threadIdx.x >> 6);
    const int lane = threadIdx.x & 63;
    const int h = w & 3;
    const int t = (w >> 2) & 2047;
    const int b = w >> 13;
    const size_t qb = ((size_t)(b * TT + t)) * 2048 + h * DH;
    const float q0 = qkvg[qb + lane], q1 = qkvg[qb + 64 + lane];

    float s[11];
#pragma unroll
    for (int o = 0; o < 11; ++o) {
        int pos = t + o - 5;
        bool valid = (pos >= 0 && pos < TT);
        float p = 0.0f;
        if (valid) {
            size_t kb = ((size_t)(b * TT + pos)) * 2048 + 512 + h * DH;
            p = q0 * qkvg[kb + lane] + q1 * qkvg[kb + 64 + lane];
        }
        for (int off = 32; off; off >>= 1) p += __shfl_xor(p, off, 64);
        s[o] = valid ? p / sqrtf(128.0f) : -1e9f;
    }
    float m = s[0];
#pragma unroll
    for (int o = 1; o < 11; ++o) m = fmaxf(m, s[o]);
    float e[11], sum = 0.0f;
#pragma unroll
    for (int o = 0; o < 11; ++o) { e[o] = expf(s[o] - m); sum += e[o]; }

    float o0 = 0.0f, o1 = 0.0f;
#pragma unroll
    for (int o = 0; o < 11; ++o) {
        int pos = t + o - 5;
        if (pos < 0 || pos >= TT) continue;
        float a = e[o] / sum;
        size_t vb = ((size_t)(b * TT + pos)) * 2048 + 1024 + h * DH;
        o0 = fmaf(a, qkvg[vb + lane], o0);
        o1 = fmaf(a, qkvg[vb + 64 + lane], o1);
    }
    const size_t ob = ((size_t)(b * TT + t)) * DIM + h * DH;
    out[ob + lane]      = o0;
    out[ob + 64 + lane] = o1;
}

// ---------------------------------------------------------------------------
// wf2f[q,s] = sum_p L[q,p] * wf[p,s]  (f64 accumulate, f32 out; GP rows)
// ---------------------------------------------------------------------------
__global__ __launch_bounds__(256) void k_conv_wf(
    const float* __restrict__ wf, float* __restrict__ wf2f)
{
    __shared__ float w[25];
    const int qq = blockIdx.x;
    if (qq >= GG) {
        for (int s = threadIdx.x; s < SS; s += 256)
            wf2f[(size_t)qq * SS + s] = 0.0f;
        return;
    }
    const int y = qq / 45, x = qq % 45;
    if (threadIdx.x < 25) {
        int ki = threadIdx.x / 5, kj = threadIdx.x % 5;
        double gi = exp(-0.5 * (double)((ki - 2) * (ki - 2)));
        double gj = exp(-0.5 * (double)((kj - 2) * (kj - 2)));
        double Z  = 1.0 + 2.0 * exp(-0.5) + 2.0 * exp(-2.0);
        w[threadIdx.x] = (float)(gi * gj / (Z * Z));
    }
    __syncthreads();
    for (int s = threadIdx.x; s < SS; s += 256) {
        double acc = 0.0;
#pragma unroll
        for (int dy = -2; dy <= 2; ++dy) {
            int yy = y + dy;
            if (yy < 0 || yy >= 45) continue;
#pragma unroll
            for (int dx = -2; dx <= 2; ++dx) {
                int xx2 = x + dx;
                if (xx2 < 0 || xx2 >= 45) continue;
                acc = fma((double)w[(dy + 2) * 5 + (dx + 2)],
                          (double)wf[(size_t)(yy * 45 + xx2) * SS + s], acc);
            }
        }
        wf2f[(size_t)qq * SS + s] = (float)acc;
    }
}

// w2pad[m][p] = p < GG ? w2[m][p] : 0   (1024 x GP)
__global__ __launch_bounds__(256) void k_pad_w2(
    const float* __restrict__ w2, float* __restrict__ w2pad)
{
    const size_t idx = (size_t)blockIdx.x * 256 + threadIdx.x;
    if (idx >= (size_t)1024 * GP) return;
    const int m = (int)(idx / GP), p = (int)(idx % GP);
    w2pad[idx] = (p < GG) ? w2[(size_t)m * GG + p] : 0.0f;
}

// c[s] = sum_q b2[q] * wf2f[q,s]  (f64 accumulate, f32 out)
__global__ __launch_bounds__(256) void k_bias_c(
    const float* __restrict__ b2, const float* __restrict__ wf2f,
    float* __restrict__ c)
{
    const int s = blockIdx.x * 4 + (threadIdx.x >> 6);
    const int lane = threadIdx.x & 63;
    double acc = 0.0;
    for (int qq = lane; qq < GG; qq += 64)
        acc = fma((double)b2[qq], (double)wf2f[(size_t)qq * SS + s], acc);
    for (int off = 32; off; off >>= 1) acc += __shfl_xor(acc, off, 64);
    if (lane == 0) c[s] = (float)acc;
}

// ---------------------------------------------------------------------------
// top-40 one-hot per row of 2048; iterative argmax, tie -> lower index
// ---------------------------------------------------------------------------
__global__ __launch_bounds__(256) void k_topk(
    const float* __restrict__ scores, float* __restrict__ sdr)
{
    __shared__ float vals[SS];
    __shared__ float rv[4];
    __shared__ int   ri[4];
    const int row = blockIdx.x;
    const float* srow = scores + (size_t)row * SS;
    float* drow = sdr + (size_t)row * SS;
    for (int i = threadIdx.x; i < SS; i += 256) { vals[i] = srow[i]; drow[i] = 0.0f; }
    __syncthreads();
    const int lane = threadIdx.x & 63, wid = threadIdx.x >> 6;
    for (int it = 0; it < KTOP; ++it) {
        float bv = -INFINITY; int bi = 0x7fffffff;
        for (int i = threadIdx.x; i < SS; i += 256) {
            float vv = vals[i];
            if (vv > bv) { bv = vv; bi = i; }
        }
        for (int off = 32; off; off >>= 1) {
            float ov = __shfl_xor(bv, off, 64);
            int   oi = __shfl_xor(bi, off, 64);
            if (ov > bv || (ov == bv && oi < bi)) { bv = ov; bi = oi; }
        }
        if (lane == 0) { rv[wid] = bv; ri[wid] = bi; }
        __syncthreads();
        if (threadIdx.x == 0) {
            float fv = rv[0]; int fi = ri[0];
            for (int wdx = 1; wdx < 4; ++wdx)
                if (rv[wdx] > fv || (rv[wdx] == fv && ri[wdx] < fi)) { fv = rv[wdx]; fi = ri[wdx]; }
            vals[fi] = -INFINITY;
            drow[fi] = 1.0f;
        }
        __syncthreads();
    }
}

// ---------------------------------------------------------------------------
// Buffer plan (identical to rounds 11/12, which passed):
//  1 embed_ln -> x@s0+0, xn@s0+3SZ
//  2 pack_qkvg -> wpack@s0+SZ, bpack@s0+SZ+1M
//  3 QKVG GEMM -> qkvg@s1
//  4 attn -> attn@s0+SZ; 5 gateres -> ctx@s0+2SZ; 6 gelu -> h1@s0[0..2SZ)
//  7 conv_wf -> wf2f@s1; 8 pad_w2 -> w2pad@s1+SZ
//  9 W splitK x4 -> Wp@s0[2SZ..4SZ); 10 add4 -> Wf@s0+2SZ
// 11 bias_c -> cvec@s0+3SZ
// 12 scores GEMM -> scores@s1
// 13 topk -> sdr@s0
// ---------------------------------------------------------------------------
extern "C" void kernel_launch(void* const* d_in, const int* in_sizes, int n_in,
                              void* d_out, int out_size, void* d_ws, size_t ws_size,
                              hipStream_t stream)
{
    (void)d_ws; (void)ws_size; (void)in_sizes; (void)n_in; (void)out_size;

    const int*   tokens = (const int*)d_in[0];
    const float* table  = (const float*)d_in[1];
    const float* ln_g   = (const float*)d_in[2];
    const float* ln_b   = (const float*)d_in[3];
    const float* wq = (const float*)d_in[4];  const float* bq = (const float*)d_in[5];
    const float* wk = (const float*)d_in[6];  const float* bk = (const float*)d_in[7];
    const float* wv = (const float*)d_in[8];  const float* bv = (const float*)d_in[9];
    const float* wo = (const float*)d_in[10]; const float* bo = (const float*)d_in[11];
    const float* wg = (const float*)d_in[12]; const float* bg = (const float*)d_in[13];
    const float* w1 = (const float*)d_in[14]; const float* b1 = (const float*)d_in[15];
    const float* w2 = (const float*)d_in[16]; const float* b2 = (const float*)d_in[17];
    const float* wf = (const float*)d_in[18];

    const size_t SZ = (size_t)NROW * DIM;          // 4,194,304 floats
    const size_t MEG = 1u << 20;
    float* slot0 = (float*)d_out;
    float* slot1 = slot0 + (size_t)NROW * SS;

    float* x     = slot0;
    float* wpack = slot0 + SZ;                 // 512x2048
    float* bpack = slot0 + SZ + MEG;           // 2048
    float* attn  = slot0 + SZ;                 // after QKVG GEMM (wpack dead)
    float* ctx   = slot0 + 2 * SZ;
    float* xn    = slot0 + 3 * SZ;
    float* qkvg  = slot1;                      // 8192x2048
    float* h1    = slot0;                      // 8192x1024
    float* wf2f  = slot1;                      // GPx2048
    float* w2pad = slot1 + SZ;                 // 1024xGP
    float* Wp    = slot0 + 2 * SZ;             // 4 partials 1024x2048 (= 2SZ)
    float* Wf    = Wp;                         // reduced in place
    float* cvec  = slot0 + 3 * SZ;             // 2048
    float* scores = slot1;
    float* sdr    = slot0;

    dim3 blk(256);
    dim3 gQKVG(16, 64);                       // N=2048
    dim3 g512(4, 64);                         // N=512
    dim3 gGelu(8, 64);                        // N=1024
    dim3 gWs(16, 8, 4);                       // W split-K x4
    dim3 gSC(16, 64);                         // N=2048

    k_embed_ln<<<NROW, blk, 0, stream>>>(tokens, table, ln_g, ln_b, x, xn);
    k_pack_qkvg<<<4096, blk, 0, stream>>>(wq, wk, wv, wg, bq, bk, bv, bg, wpack, bpack);
    k_gemm_f32<EPI_QKVG>     <<<gQKVG, blk, 0, stream>>>(xn, wpack, bpack, qkvg, NROW, 2048, DIM, nullptr, nullptr, 0);
    k_attn                   <<<NROW,  blk, 0, stream>>>(qkvg, attn);
    k_gemm_f32<EPI_GATERES>  <<<g512,  blk, 0, stream>>>(attn, wo, bo, ctx, NROW, DIM, DIM, x, qkvg + 1536, 2048);
    k_gemm_f32<EPI_GELU>     <<<gGelu, blk, 0, stream>>>(ctx, w1, b1, h1, NROW, 2 * DIM, DIM, nullptr, nullptr, 0);
    k_conv_wf                <<<GP,    blk, 0, stream>>>(wf, wf2f);
    k_pad_w2                 <<<(1024 * GP + 255) / 256, blk, 0, stream>>>(w2, w2pad);
    k_gemm_f32<EPI_NONE, 512><<<gWs,   blk, 0, stream>>>(w2pad, wf2f, nullptr, Wp, 1024, SS, GP, nullptr, nullptr, 0);
    k_add4                   <<<2048,  blk, 0, stream>>>((float4*)Wp, 524288);
    k_bias_c                 <<<SS/4,  blk, 0, stream>>>(b2, wf2f, cvec);
    k_gemm_f32<EPI_BIAS>     <<<gSC,   blk, 0, stream>>>(h1, Wf, cvec, scores, NROW, SS, 2 * DIM, nullptr, nullptr, 0);
    k_topk                   <<<NROW,  blk, 0, stream>>>(scores, sdr);
}